// Round 1
// baseline (163.036 us; speedup 1.0000x reference)
//
#include <hip/hip_runtime.h>
#include <hip/hip_bf16.h>

#define IN_F 4096
#define OUT_F 11008
#define TOKENS 32
#define RANK 16
#define KSPLIT 8
#define KSLICE (IN_F / KSPLIT)  // 512

typedef unsigned short u16;
typedef __attribute__((ext_vector_type(8))) short bf16x8;
typedef __attribute__((ext_vector_type(4))) float f32x4;

__device__ const float NF4_d[16] = {
    -1.0f, -0.6961928009986877f, -0.5250730514526367f, -0.39491748809814453f,
    -0.28444138169288635f, -0.18477343022823334f, -0.09105003625154495f, 0.0f,
    0.07958029955625534f, 0.16093020141124725f, 0.24611230194568634f,
    0.33791524171829224f, 0.44070982933044434f, 0.5626170039176941f,
    0.7229568362236023f, 1.0f};

static __device__ __forceinline__ unsigned pk2(float a, float b) {
    __hip_bfloat162 h = __float22bfloat162_rn(make_float2(a, b));
    unsigned u;
    __builtin_memcpy(&u, &h, 4);
    return u;
}

// k1: convert x (fp32) -> bf16 into ws
__global__ void cvt_x(const float* __restrict__ x, u16* __restrict__ xbf) {
    int i4 = blockIdx.x * 256 + threadIdx.x;  // float4 index, 32768 total
    float4 v = ((const float4*)x)[i4];
    uint2 o;
    o.x = pk2(v.x, v.y);
    o.y = pk2(v.z, v.w);
    ((uint2*)xbf)[i4] = o;
}

// k2: xa[t][r] = sum_i x[t][i] * A[r][i]   (512 blocks, one (t,r) each)
__global__ void lora_xa(const float* __restrict__ x, const float* __restrict__ A,
                        float* __restrict__ xa) {
    int b = blockIdx.x;  // 0..511
    int t = b >> 4, r = b & 15;
    const float4* xr = (const float4*)(x + t * IN_F);
    const float4* ar = (const float4*)(A + r * IN_F);
    float s = 0.f;
    for (int c = 0; c < 4; ++c) {
        int j = c * 256 + threadIdx.x;
        float4 xv = xr[j], av = ar[j];
        s += xv.x * av.x + xv.y * av.y + xv.z * av.z + xv.w * av.w;
    }
    __shared__ float red[256];
    red[threadIdx.x] = s;
    __syncthreads();
    for (int st = 128; st > 0; st >>= 1) {
        if (threadIdx.x < st) red[threadIdx.x] += red[threadIdx.x + st];
        __syncthreads();
    }
    if (threadIdx.x == 0) xa[b] = red[0];
}

// k3: out[t][o] = SCALING * sum_r xa[t][r] * B[o][r]  (initializes out)
__global__ void lora_out(const float* __restrict__ xa, const float* __restrict__ B,
                         float* __restrict__ out) {
    int idx = blockIdx.x * 256 + threadIdx.x;  // 352256 total
    int t = idx / OUT_F;
    int o = idx - t * OUT_F;
    const float4* br = (const float4*)(B + o * RANK);
    const float4* xr = (const float4*)(xa + t * RANK);
    float acc = 0.f;
    for (int c = 0; c < 4; ++c) {
        float4 bv = br[c], xv = xr[c];
        acc += bv.x * xv.x + bv.y * xv.y + bv.z * xv.z + bv.w * xv.w;
    }
    out[idx] = acc;  // SCALING = 1.0; plain store initializes out
}

// main: base GEMM via MFMA bf16, K-split partials atomically added
__global__ __launch_bounds__(256) void qlora_main(const int* __restrict__ packed,
                                                  const float* __restrict__ scales,
                                                  const u16* __restrict__ xbf,
                                                  float* __restrict__ out) {
    __shared__ u16 xs[32 * 520];     // 32 tokens x 512 k, pad 8 bf16/row
    __shared__ float2 tbl[256];      // byte -> (hi_code, lo_code)
    const int tid = threadIdx.x;
    const int kbase = blockIdx.y * KSLICE;

    // build dequant pair-table
    tbl[tid] = make_float2(NF4_d[tid >> 4], NF4_d[tid & 15]);

    // stage x slice (bf16) into LDS: 32 rows x 512 cols
    for (int it = 0; it < 8; ++it) {
        int row = it * 4 + (tid >> 6);
        int c8 = tid & 63;
        const uint4* src = (const uint4*)(xbf + row * IN_F + kbase + c8 * 8);
        *(uint4*)(xs + row * 520 + c8 * 8) = *src;
    }
    __syncthreads();

    const int lane = tid & 63;
    const int wv = tid >> 6;
    const int n = lane & 15;   // output within wave tile
    const int q = lane >> 4;   // k-subblock
    const int o = blockIdx.x * 64 + wv * 16 + n;
    const int rowbase = o * 2048;  // int32 (=byte) elements per weight row

    f32x4 acc0 = {0.f, 0.f, 0.f, 0.f};
    f32x4 acc1 = {0.f, 0.f, 0.f, 0.f};
    const u16* xrow0 = xs + n * 520 + q * 8;
    const u16* xrow1 = xs + (n + 16) * 520 + q * 8;

    for (int kk = 0; kk < KSLICE; kk += 32) {
        int k = kbase + kk;
        // 4 bytes = 8 nibbles of row o, k..k+31 for this lane's k-subblock
        int4 pw = *(const int4*)(packed + rowbase + (k >> 1) + q * 4);
        float s = scales[o * 64 + ((k + q * 8) >> 6)];

        float2 c0 = tbl[pw.x & 255];
        float2 c1 = tbl[pw.y & 255];
        float2 c2 = tbl[pw.z & 255];
        float2 c3 = tbl[pw.w & 255];
        uint4 bu;
        bu.x = pk2(c0.x * s, c0.y * s);
        bu.y = pk2(c1.x * s, c1.y * s);
        bu.z = pk2(c2.x * s, c2.y * s);
        bu.w = pk2(c3.x * s, c3.y * s);
        bf16x8 bfrag;
        __builtin_memcpy(&bfrag, &bu, 16);

        bf16x8 a0 = *(const bf16x8*)(xrow0 + kk);
        bf16x8 a1 = *(const bf16x8*)(xrow1 + kk);
        acc0 = __builtin_amdgcn_mfma_f32_16x16x32_bf16(a0, bfrag, acc0, 0, 0, 0);
        acc1 = __builtin_amdgcn_mfma_f32_16x16x32_bf16(a1, bfrag, acc1, 0, 0, 0);
    }

    // C/D layout: col = lane&15 (output), row = (lane>>4)*4 + reg (token)
    for (int r = 0; r < 4; ++r) {
        int t = q * 4 + r;
        atomicAdd(out + t * OUT_F + o, acc0[r]);
        atomicAdd(out + (t + 16) * OUT_F + o, acc1[r]);
    }
}

extern "C" void kernel_launch(void* const* d_in, const int* in_sizes, int n_in,
                              void* d_out, int out_size, void* d_ws, size_t ws_size,
                              hipStream_t stream) {
    const float* x = (const float*)d_in[0];
    const int* packed = (const int*)d_in[1];
    const float* scales = (const float*)d_in[2];
    const float* lora_A = (const float*)d_in[3];
    const float* lora_B = (const float*)d_in[4];
    float* out = (float*)d_out;

    u16* xbf = (u16*)d_ws;                                   // 262144 B
    float* xa = (float*)((char*)d_ws + TOKENS * IN_F * 2);   // 2048 B

    cvt_x<<<128, 256, 0, stream>>>(x, xbf);
    lora_xa<<<512, 256, 0, stream>>>(x, lora_A, xa);
    lora_out<<<(TOKENS * OUT_F) / 256, 256, 0, stream>>>(xa, lora_B, out);
    qlora_main<<<dim3(OUT_F / 64, KSPLIT), 256, 0, stream>>>(packed, scales, xbf, out);
}

// Round 2
// 155.610 us; speedup vs baseline: 1.0477x; 1.0477x over previous
//
#include <hip/hip_runtime.h>
#include <hip/hip_bf16.h>

#define IN_F 4096
#define OUT_F 11008
#define TOKENS 32
#define RANK 16
#define KSPLIT 8
#define KSLICE (IN_F / KSPLIT)  // 512
#define XPAD 520                // u16 per LDS x-row (512 data + 8 pad)

typedef unsigned short u16;
typedef __attribute__((ext_vector_type(8))) short bf16x8;
typedef __attribute__((ext_vector_type(4))) float f32x4;

__device__ const float NF4_d[16] = {
    -1.0f, -0.6961928009986877f, -0.5250730514526367f, -0.39491748809814453f,
    -0.28444138169288635f, -0.18477343022823334f, -0.09105003625154495f, 0.0f,
    0.07958029955625534f, 0.16093020141124725f, 0.24611230194568634f,
    0.33791524171829224f, 0.44070982933044434f, 0.5626170039176941f,
    0.7229568362236023f, 1.0f};

static __device__ __forceinline__ unsigned pk2(float a, float b) {
    __hip_bfloat162 h = __float22bfloat162_rn(make_float2(a, b));
    unsigned u;
    __builtin_memcpy(&u, &h, 4);
    return u;
}

// prep: blocks 0..511 compute xa[t][r]; blocks 512..639 convert x -> bf16
__global__ void prep(const float* __restrict__ x, const float* __restrict__ A,
                     u16* __restrict__ xbf, float* __restrict__ xa) {
    __shared__ float red[256];
    if (blockIdx.x >= 512) {
        int i4 = (blockIdx.x - 512) * 256 + threadIdx.x;  // 32768 float4s
        float4 v = ((const float4*)x)[i4];
        uint2 o;
        o.x = pk2(v.x, v.y);
        o.y = pk2(v.z, v.w);
        ((uint2*)xbf)[i4] = o;
        return;
    }
    int b = blockIdx.x;  // 0..511
    int t = b >> 4, r = b & 15;
    const float4* xr = (const float4*)(x + t * IN_F);
    const float4* ar = (const float4*)(A + r * IN_F);
    float s = 0.f;
    for (int c = 0; c < 4; ++c) {
        int j = c * 256 + threadIdx.x;
        float4 xv = xr[j], av = ar[j];
        s += xv.x * av.x + xv.y * av.y + xv.z * av.z + xv.w * av.w;
    }
    red[threadIdx.x] = s;
    __syncthreads();
    for (int st = 128; st > 0; st >>= 1) {
        if (threadIdx.x < st) red[threadIdx.x] += red[threadIdx.x + st];
        __syncthreads();
    }
    if (threadIdx.x == 0) xa[b] = red[0];
}

// lora_out: out[t][o] = sum_r xa[t][r] * B[o][r]   (initializes out)
__global__ void lora_out(const float* __restrict__ xa, const float* __restrict__ B,
                         float* __restrict__ out) {
    int idx = blockIdx.x * 256 + threadIdx.x;  // 352256 total
    int t = idx / OUT_F;
    int o = idx - t * OUT_F;
    const float4* br = (const float4*)(B + o * RANK);
    const float4* xr = (const float4*)(xa + t * RANK);
    float acc = 0.f;
    for (int c = 0; c < 4; ++c) {
        float4 bv = br[c], xv = xr[c];
        acc += bv.x * xv.x + bv.y * xv.y + bv.z * xv.z + bv.w * xv.w;
    }
    out[idx] = acc;  // SCALING = 1.0
}

// main: NF4 dequant + bf16 MFMA GEMM, K-split partials via atomicAdd
__global__ __launch_bounds__(256) void qlora_main(const int* __restrict__ packed,
                                                  const float* __restrict__ scales,
                                                  const u16* __restrict__ xbf,
                                                  float* __restrict__ out) {
    __shared__ u16 xs[32 * XPAD];  // 32 tokens x 512 k (bf16)
    __shared__ float2 tbl[256];    // byte -> (hi_code, lo_code)
    __shared__ float sl[64 * 9];   // 64 rows x 8 k-groups, stride 9 (pad)
    const int tid = threadIdx.x;
    const int kbase = blockIdx.y * KSLICE;
    const int obase = blockIdx.x * 64;

    tbl[tid] = make_float2(NF4_d[tid >> 4], NF4_d[tid & 15]);

    // stage scales: rows obase..obase+63, groups (kbase>>6)..+7
    {
        int r = tid >> 3, g = tid & 7;
        int g0 = (kbase >> 6);
        sl[r * 9 + g] = scales[(obase + r) * 64 + g0 + g];
        sl[(r + 32) * 9 + g] = scales[(obase + r + 32) * 64 + g0 + g];
    }

    // stage x slice: 32 rows x 512 bf16 (each wave: 1 KB contiguous per row)
    for (int it = 0; it < 8; ++it) {
        int row = it * 4 + (tid >> 6);
        int c8 = tid & 63;
        *(uint4*)(xs + row * XPAD + c8 * 8) =
            *(const uint4*)(xbf + row * IN_F + kbase + c8 * 8);
    }
    __syncthreads();

    const int lane = tid & 63;
    const int wv = tid >> 6;
    const int n = lane & 15;  // output col within wave tile
    const int q = lane >> 4;  // k-subblock
    const int o = obase + wv * 16 + n;

    // step s (k = kbase + 32*s) reads int4 at element offset s*16 + q*4
    const int4* pp = (const int4*)(packed + o * 2048 + (kbase >> 1)) + q;

    f32x4 acc0 = {0.f, 0.f, 0.f, 0.f};
    f32x4 acc1 = {0.f, 0.f, 0.f, 0.f};
    const u16* xr0 = xs + n * XPAD + q * 8;
    const u16* xr1 = xs + (n + 16) * XPAD + q * 8;
    const float* slp = sl + (wv * 16 + n) * 9;

    int4 c0 = pp[0];
    int4 c1 = pp[4];

#pragma unroll
    for (int s = 0; s < 16; s += 2) {
        int4 n0 = c0, n1 = c1;
        if (s + 2 < 16) {
            n0 = pp[(s + 2) * 4];
            n1 = pp[(s + 3) * 4];
        }
        float sc = slp[s >> 1];  // same 64-group for steps s, s+1

        // step s
        {
            float2 d0 = tbl[c0.x & 255];
            float2 d1 = tbl[c0.y & 255];
            float2 d2 = tbl[c0.z & 255];
            float2 d3 = tbl[c0.w & 255];
            uint4 bu;
            bu.x = pk2(d0.x * sc, d0.y * sc);
            bu.y = pk2(d1.x * sc, d1.y * sc);
            bu.z = pk2(d2.x * sc, d2.y * sc);
            bu.w = pk2(d3.x * sc, d3.y * sc);
            bf16x8 bfrag;
            __builtin_memcpy(&bfrag, &bu, 16);
            bf16x8 a0 = *(const bf16x8*)(xr0 + s * 32);
            bf16x8 a1 = *(const bf16x8*)(xr1 + s * 32);
            acc0 = __builtin_amdgcn_mfma_f32_16x16x32_bf16(a0, bfrag, acc0, 0, 0, 0);
            acc1 = __builtin_amdgcn_mfma_f32_16x16x32_bf16(a1, bfrag, acc1, 0, 0, 0);
        }
        // step s+1
        {
            float2 d0 = tbl[c1.x & 255];
            float2 d1 = tbl[c1.y & 255];
            float2 d2 = tbl[c1.z & 255];
            float2 d3 = tbl[c1.w & 255];
            uint4 bu;
            bu.x = pk2(d0.x * sc, d0.y * sc);
            bu.y = pk2(d1.x * sc, d1.y * sc);
            bu.z = pk2(d2.x * sc, d2.y * sc);
            bu.w = pk2(d3.x * sc, d3.y * sc);
            bf16x8 bfrag;
            __builtin_memcpy(&bfrag, &bu, 16);
            bf16x8 a0 = *(const bf16x8*)(xr0 + (s + 1) * 32);
            bf16x8 a1 = *(const bf16x8*)(xr1 + (s + 1) * 32);
            acc0 = __builtin_amdgcn_mfma_f32_16x16x32_bf16(a0, bfrag, acc0, 0, 0, 0);
            acc1 = __builtin_amdgcn_mfma_f32_16x16x32_bf16(a1, bfrag, acc1, 0, 0, 0);
        }
        c0 = n0;
        c1 = n1;
    }

    // C/D layout: col = lane&15 (output o), row = (lane>>4)*4 + reg (token)
    for (int r = 0; r < 4; ++r) {
        int t = q * 4 + r;
        atomicAdd(out + t * OUT_F + o, acc0[r]);
        atomicAdd(out + (t + 16) * OUT_F + o, acc1[r]);
    }
}

extern "C" void kernel_launch(void* const* d_in, const int* in_sizes, int n_in,
                              void* d_out, int out_size, void* d_ws, size_t ws_size,
                              hipStream_t stream) {
    const float* x = (const float*)d_in[0];
    const int* packed = (const int*)d_in[1];
    const float* scales = (const float*)d_in[2];
    const float* lora_A = (const float*)d_in[3];
    const float* lora_B = (const float*)d_in[4];
    float* out = (float*)d_out;

    u16* xbf = (u16*)d_ws;                                  // 262144 B
    float* xa = (float*)((char*)d_ws + TOKENS * IN_F * 2);  // 2048 B

    prep<<<640, 256, 0, stream>>>(x, lora_A, xbf, xa);
    lora_out<<<(TOKENS * OUT_F) / 256, 256, 0, stream>>>(xa, lora_B, out);
    qlora_main<<<dim3(OUT_F / 64, KSPLIT), 256, 0, stream>>>(packed, scales, xbf, out);
}